// Round 9
// baseline (174.595 us; speedup 1.0000x reference)
//
#include <hip/hip_runtime.h>
#include <hip/hip_bf16.h>

#define BATCH 64
#define SEQT  512
#define EMB   1024
#define HID   2048
#define VOC   32000
#define KSPLIT 8

using bf16x8 = __attribute__((ext_vector_type(8))) __bf16;
using f32x4  = __attribute__((ext_vector_type(4))) float;

__device__ __forceinline__ void split2(float x, __bf16& hi, __bf16& lo) {
  hi = (__bf16)x;
  lo = (__bf16)(x - (float)hi);
}

// ---------------------------------------------------------------------------
// Layer kernel: h_out = tanh(A @ W + bias), split-bf16 (3 MFMA products,
// f32 accumulate), 16x16x32 MFMA. 256 blocks = 128 N-tiles x 2 M-halves,
// 1024 thr = 16 waves, K-split 16 within block, LDS reduce. All W AND A
// loads hoisted ahead of compute -> single latency exposure per wave.
// PACKOUT: epilogue writes f16x2-packed hp[kp][64m] + f32 hf[k][64m]
// (consumed by out_main) instead of split-bf16 planes.
// ---------------------------------------------------------------------------
template <int KTOT, bool GATHER, bool PACKOUT>
__global__ __launch_bounds__(1024) void layer_kernel(
    const int* __restrict__ X, const float* __restrict__ emb,
    const __hip_bfloat16* __restrict__ hin_hi,
    const __hip_bfloat16* __restrict__ hin_lo,
    const float* __restrict__ W, const float* __restrict__ bias,
    __hip_bfloat16* __restrict__ hout_hi,
    __hip_bfloat16* __restrict__ hout_lo,
    unsigned* __restrict__ hp, float* __restrict__ hf) {
  constexpr int KCHUNK = KTOT / 16;   // 128 (HID) / 64 (EMB)
  constexpr int KSTEPS = KCHUNK / 32; // 4 / 2
  __shared__ float red[16 * 16 * 40];  // [wave][n][m_local pad 32->40]

  const int tid = threadIdx.x;
  const int w = tid >> 6;
  const int l = tid & 63;
  const int ln = l & 15;
  const int lg = l >> 4;
  const int n0 = (blockIdx.x & 127) * 16;
  const int mb = (blockIdx.x >> 7) * 32;  // M-half base

  f32x4 acc[2];
#pragma unroll
  for (int mt = 0; mt < 2; ++mt) acc[mt] = f32x4{0.f, 0.f, 0.f, 0.f};

  const float* grow[2];
#pragma unroll
  for (int mt = 0; mt < 2; ++mt) {
    if constexpr (GATHER) {
      const int m = mb + ln + 16 * mt;
      const int tok = X[m * SEQT + (SEQT - 1)];
      grow[mt] = emb + (size_t)tok * EMB;
    } else {
      grow[mt] = nullptr;
    }
  }

  const int kwave = w * KCHUNK + lg * 8;
  const float* Wc = W + n0 + ln;

  // hoist ALL W loads for this wave's K-chunk
  float wv[KSTEPS * 8];
#pragma unroll
  for (int j = 0; j < KSTEPS * 8; ++j)
    wv[j] = Wc[(size_t)(kwave + (j >> 3) * 32 + (j & 7)) * HID];

  // hoist ALL A fragments (split-bf16 planes)
  bf16x8 Ah[2][KSTEPS], Al[2][KSTEPS];
  if constexpr (GATHER) {
#pragma unroll
    for (int mt = 0; mt < 2; ++mt)
#pragma unroll
      for (int ks = 0; ks < KSTEPS; ++ks) {
        const float* p = grow[mt] + kwave + ks * 32;
        const f32x4 v0 = *reinterpret_cast<const f32x4*>(p);
        const f32x4 v1 = *reinterpret_cast<const f32x4*>(p + 4);
#pragma unroll
        for (int i = 0; i < 4; ++i) {
          __bf16 h_, l_;
          split2(v0[i], h_, l_);
          Ah[mt][ks][i] = h_;
          Al[mt][ks][i] = l_;
          split2(v1[i], h_, l_);
          Ah[mt][ks][4 + i] = h_;
          Al[mt][ks][4 + i] = l_;
        }
      }
  } else {
#pragma unroll
    for (int mt = 0; mt < 2; ++mt)
#pragma unroll
      for (int ks = 0; ks < KSTEPS; ++ks) {
        const size_t off = (size_t)(mb + ln + 16 * mt) * KTOT + kwave + ks * 32;
        Ah[mt][ks] = *reinterpret_cast<const bf16x8*>(hin_hi + off);
        Al[mt][ks] = *reinterpret_cast<const bf16x8*>(hin_lo + off);
      }
  }

#pragma unroll
  for (int ks = 0; ks < KSTEPS; ++ks) {
    bf16x8 bhi, blo;
#pragma unroll
    for (int i = 0; i < 8; ++i) {
      __bf16 h_, l_;
      split2(wv[ks * 8 + i], h_, l_);
      bhi[i] = h_;
      blo[i] = l_;
    }
#pragma unroll
    for (int mt = 0; mt < 2; ++mt) {
      acc[mt] = __builtin_amdgcn_mfma_f32_16x16x32_bf16(Ah[mt][ks], bhi, acc[mt], 0, 0, 0);
      acc[mt] = __builtin_amdgcn_mfma_f32_16x16x32_bf16(Al[mt][ks], bhi, acc[mt], 0, 0, 0);
      acc[mt] = __builtin_amdgcn_mfma_f32_16x16x32_bf16(Ah[mt][ks], blo, acc[mt], 0, 0, 0);
    }
  }

  // stash: red[(w*16+n)*40 + m_local]; acc[mt][j] -> m_local = mt*16+lg*4+j
  float* dst = &red[(w * 16 + ln) * 40 + lg * 4];
#pragma unroll
  for (int mt = 0; mt < 2; ++mt)
    *reinterpret_cast<f32x4*>(dst + mt * 16) = acc[mt];

  __syncthreads();

  if (tid < 512) {
    const int m = tid >> 4, n = tid & 15;  // m_local 0..31
    float s = 0.f;
#pragma unroll
    for (int ww = 0; ww < 16; ++ww) s += red[(ww * 16 + n) * 40 + m];
    s += bias[n0 + n];
    const float hval = tanhf(s);
    if constexpr (PACKOUT) {
      // pack adjacent n-columns (k-index c = n0+n) into f16x2; also f32 copy
      const int c = n0 + n;
      const int mg = mb + m;
      hf[(size_t)c * 64 + mg] = hval;
      const float partner = __shfl_xor(hval, 1, 64);
      if ((tid & 1) == 0) {
        using fp2 = __attribute__((ext_vector_type(2))) __fp16;
        const fp2 pk = __builtin_amdgcn_cvt_pkrtz(hval, partner);
        hp[(size_t)(c >> 1) * 64 + mg] = __builtin_bit_cast(unsigned, pk);
      }
    } else {
      __bf16 h_, l_;
      split2(hval, h_, l_);
      const size_t off = (size_t)(mb + m) * HID + (n0 + n);
      hout_hi[off] = *reinterpret_cast<__hip_bfloat16*>(&h_);
      hout_lo[off] = *reinterpret_cast<__hip_bfloat16*>(&l_);
    }
  }
}

// ---------------------------------------------------------------------------
// out_main: scratch[kq][m][n] = h[:,kq-range] @ W_hy[kq-range,:].
// Pure VALU streaming: lane owns col n, W read coalesced/nontemporal with an
// EXPLICIT 4-buffer register pipeline (12 loads = 3 KB/wave in flight,
// ~1000 cyc lead per chunk); h enters via the scalar pipe (uniform address).
// v_dot2_f32_f16, f32 accumulate. No LDS, no barriers.
// scratch stores are PLAIN (not nontemporal): nt stores use a no-allocate
// policy, and the next kernel's plain loads can hit stale poisoned L2 lines
// (round-8 post-timing divergence). nt only for final out + W streams.
// Grid: 125 n-tiles x KSPLIT(8) = 1000 blocks x 256 thr, 4 blocks/CU.
// ---------------------------------------------------------------------------
__global__ __launch_bounds__(256, 4) void out_main(
    const unsigned* __restrict__ hp, const float* __restrict__ hf,
    const float* __restrict__ Why, float* __restrict__ scratch) {
  const int tid = threadIdx.x;
  const int nt = blockIdx.x % 125;
  const int kq = blockIdx.x / 125;
  const int n = nt * 256 + tid;

  float acc[64];
#pragma unroll
  for (int m = 0; m < 64; ++m) acc[m] = 0.f;

  constexpr int KPB = HID / KSPLIT / 2;  // 128 k-pairs per block
  constexpr int NCH = KPB / 2;           // 64 chunks of 2 kp (4 k-rows)
  const int kp0 = kq * KPB;
  const float* W0 = Why + n;

#if __has_builtin(__builtin_amdgcn_fdot2)
  using h2  = __attribute__((ext_vector_type(2))) _Float16;
  using fp2 = __attribute__((ext_vector_type(2))) __fp16;

#define LOADC(c_, buf_)                                                      \
  {                                                                          \
    const int cc_ = (c_) & (NCH - 1);                                        \
    const size_t kb_ = (size_t)(kp0 + 2 * cc_) * 2;                          \
    buf_[0] = __builtin_nontemporal_load(W0 + (kb_ + 0) * VOC);              \
    buf_[1] = __builtin_nontemporal_load(W0 + (kb_ + 1) * VOC);              \
    buf_[2] = __builtin_nontemporal_load(W0 + (kb_ + 2) * VOC);              \
    buf_[3] = __builtin_nontemporal_load(W0 + (kb_ + 3) * VOC);              \
  }

#define COMPC(c_, buf_)                                                      \
  {                                                                          \
    _Pragma("unroll") for (int j_ = 0; j_ < 2; ++j_) {                       \
      const int kp_ = kp0 + 2 * (c_) + j_;                                   \
      const fp2 raw_ =                                                       \
          __builtin_amdgcn_cvt_pkrtz(buf_[2 * j_], buf_[2 * j_ + 1]);        \
      const h2 wp_ = __builtin_bit_cast(h2, raw_);                           \
      const unsigned* hk_ = hp + (size_t)kp_ * 64;                           \
      _Pragma("unroll") for (int m_ = 0; m_ < 64; ++m_) {                    \
        acc[m_] = __builtin_amdgcn_fdot2(                                    \
            wp_, __builtin_bit_cast(h2, hk_[m_]), acc[m_], false);           \
      }                                                                      \
    }                                                                        \
  }

  float bA[4], bB[4], bC[4], bD[4];
  LOADC(0, bA);
  LOADC(1, bB);
  LOADC(2, bC);
  LOADC(3, bD);
#pragma unroll 1
  for (int c = 0; c < NCH; c += 4) {
    COMPC(c + 0, bA);
    LOADC(c + 4, bA);
    COMPC(c + 1, bB);
    LOADC(c + 5, bB);
    COMPC(c + 2, bC);
    LOADC(c + 6, bC);
    COMPC(c + 3, bD);
    LOADC(c + 7, bD);
  }
#undef COMPC
#undef LOADC
#else
  const int k0 = kq * (HID / KSPLIT);
#pragma unroll 2
  for (int k = k0; k < k0 + HID / KSPLIT; ++k) {
    const float wv = __builtin_nontemporal_load(W0 + (size_t)k * VOC);
    const float* hk = hf + (size_t)k * 64;
#pragma unroll
    for (int m = 0; m < 64; ++m) acc[m] = fmaf(wv, hk[m], acc[m]);
  }
#endif

  // PLAIN stores (kernel-to-kernel data must go through the normal L2 path)
  float* sc = scratch + (size_t)kq * ((size_t)BATCH * VOC) + n;
#pragma unroll
  for (int m = 0; m < 64; ++m) sc[(size_t)m * VOC] = acc[m];
}

// ---------------------------------------------------------------------------
// reduce_out: out[m][n] = sum_q scratch[q][m][n] + b_y[n].
// Grid (125, 64) x 256 thr; scratch is L2/L3-hot.
// ---------------------------------------------------------------------------
__global__ __launch_bounds__(256) void reduce_out(
    const float* __restrict__ scratch, const float* __restrict__ by,
    float* __restrict__ out) {
  const int n = blockIdx.x * 256 + threadIdx.x;
  const int m = blockIdx.y;
  float s = by[n];
#pragma unroll
  for (int q = 0; q < KSPLIT; ++q)
    s += scratch[(size_t)q * ((size_t)BATCH * VOC) + (size_t)m * VOC + n];
  __builtin_nontemporal_store(s, out + (size_t)m * VOC + n);
}

extern "C" void kernel_launch(void* const* d_in, const int* in_sizes, int n_in,
                              void* d_out, int out_size, void* d_ws,
                              size_t ws_size, hipStream_t stream) {
  const int* X = (const int*)d_in[0];
  const float* emb = (const float*)d_in[1];
  const float* W_xh = (const float*)d_in[2];
  const float* W_hh = (const float*)d_in[3];
  const float* W_hy = (const float*)d_in[4];
  const float* b_h = (const float*)d_in[5];
  const float* b_y = (const float*)d_in[6];
  float* out = (float*)d_out;

  char* ws = (char*)d_ws;
  const size_t PLANE = (size_t)BATCH * HID;  // elements
  __hip_bfloat16* hA_hi = (__hip_bfloat16*)ws;
  __hip_bfloat16* hA_lo = hA_hi + PLANE;
  __hip_bfloat16* hB_hi = hA_lo + PLANE;
  __hip_bfloat16* hB_lo = hB_hi + PLANE;
  char* p = ws + 4 * PLANE * sizeof(__hip_bfloat16);
  unsigned* hp = (unsigned*)p;                 // 1024 kp x 64 m u32
  p += (size_t)(HID / 2) * BATCH * sizeof(unsigned);
  float* hf = (float*)p;                       // 2048 k x 64 m f32
  p += (size_t)HID * BATCH * sizeof(float);
  float* scratch = (float*)p;                  // KSPLIT x 64 x 32000 f32

  dim3 blk(1024), grd(256);
  layer_kernel<EMB, true, false><<<grd, blk, 0, stream>>>(
      X, emb, nullptr, nullptr, W_xh, b_h, hA_hi, hA_lo, nullptr, nullptr);
  layer_kernel<HID, false, false><<<grd, blk, 0, stream>>>(
      nullptr, nullptr, hA_hi, hA_lo, W_hh, b_h, hB_hi, hB_lo, nullptr, nullptr);
  layer_kernel<HID, false, false><<<grd, blk, 0, stream>>>(
      nullptr, nullptr, hB_hi, hB_lo, W_hh, b_h, hA_hi, hA_lo, nullptr, nullptr);
  layer_kernel<HID, false, false><<<grd, blk, 0, stream>>>(
      nullptr, nullptr, hA_hi, hA_lo, W_hh, b_h, hB_hi, hB_lo, nullptr, nullptr);
  layer_kernel<HID, false, true><<<grd, blk, 0, stream>>>(
      nullptr, nullptr, hB_hi, hB_lo, W_hh, b_h, nullptr, nullptr, hp, hf);

  out_main<<<dim3(125 * KSPLIT), dim3(256), 0, stream>>>(hp, hf, W_hy, scratch);
  reduce_out<<<dim3(125, 64), dim3(256), 0, stream>>>(scratch, b_y, out);
}